// Round 16
// baseline (2132.898 us; speedup 1.0000x reference)
//
#include <hip/hip_runtime.h>

typedef __attribute__((ext_vector_type(8))) _Float16 f16x8;
typedef __attribute__((ext_vector_type(4))) float    f32x4;

#define HD    256
#define CIN   16
#define TIN   48
#define TOUT  24
#define COUT  8
#define MB    16            // batch rows per block -> 512 blocks = 2/CU
#define KPAD  296           // padded row stride (halves) for hF
#define KT_ENC 9            // K = 288 (h 256 | x 16 | pad 16)
#define KT_DEC 8            // K = 256
#define WE_HALVES (KT_ENC*4*16*512)   // 294912
#define WD_HALVES (KT_DEC*4*16*512)   // 262144
#define PREP_TOTAL (WE_HALVES + WD_HALVES)

template <int N> struct KTag { static constexpr int val = N; };

// Fragment-major fp16 weights: frag id = kt*64 + g*16 + ntile, each frag is
// 64 lanes x 8 halves with b_frag[lane][s] = W[k = kt*32 + (lane>>4)*8 + s]
//                                             [col = g*256 + ntile*16 + (lane&15)]
__global__ void prep_frags(const float* __restrict__ enc_Wih,
                           const float* __restrict__ enc_Whh,
                           const float* __restrict__ dec_Whh,
                           _Float16* __restrict__ wf)
{
    int p = blockIdx.x * blockDim.x + threadIdx.x;
    if (p >= PREP_TOTAL) return;
    int lane = (p >> 3) & 63;
    int s    = p & 7;
    int kq   = ((lane >> 4) << 3) + s;
    int l15  = lane & 15;
    float v;
    if (p < WE_HALVES) {
        int frag = p >> 9;
        int kt = frag >> 6, g = (frag >> 4) & 3, ntile = frag & 15;
        int k   = kt * 32 + kq;
        int row = g * 256 + ntile * 16 + l15;
        v = 0.0f;
        if (k < 256)      v = enc_Whh[row * 256 + k];
        else if (k < 272) v = enc_Wih[row * 16 + (k - 256)];
    } else {
        int q = p - WE_HALVES;
        int frag = q >> 9;
        int kt = frag >> 6, g = (frag >> 4) & 3, ntile = frag & 15;
        int k   = kt * 32 + kq;
        int row = g * 256 + ntile * 16 + l15;
        v = dec_Whh[row * 256 + k];
    }
    wf[p] = (_Float16)v;
}

__device__ __forceinline__ float sigm(float v) {
    return __builtin_amdgcn_rcpf(1.0f + __expf(-v));
}
__device__ __forceinline__ float tanh_f(float v) {
    return 1.0f - 2.0f * __builtin_amdgcn_rcpf(1.0f + __expf(2.0f * v));
}

// Async global->LDS stage of one 1KB weight fragment: 64 lanes x 16B.
__device__ __forceinline__ void gld_lds16(const _Float16* g, _Float16* l) {
    __builtin_amdgcn_global_load_lds(
        (const __attribute__((address_space(1))) void*)g,
        (__attribute__((address_space(3))) void*)l, 16, 0, 0);
}

// grid = 512 blocks = 2/CU, 512 threads = 8 waves. Wave w owns the ntile
// PAIR (2w, 2w+1): all 4 gates, one 16-row M-tile (MB=16). r12 two-barrier
// scheme + 8-slot static ring, stage f+7 / vmcnt(7) / consume f.
//
// RACE FIX vs r15/r13 (both failed ~4.2e-3): between body(f-1)'s ds_read of
// slot (f-1)&7 and stagef(f+7)'s DMA write to THE SAME slot there was no
// scheduling fence -- the "memory"-clobber asm only pins ops against the asm
// statements, not against each other inside the region, so the scheduler
// could hoist the global_load_lds above the ds_read; an L2-hit DMA (~100cy)
// then lands before the read drains -> occasional frag corruption (r12
// passes by scheduler luck; r14's runtime index blocked the hoist). The
// sched_barrier(0) at the TOP of each iteration closes the window.
__global__ __launch_bounds__(512, 4) void seq2seq_mfma(
    const float* __restrict__ x,
    const _Float16* __restrict__ wf,
    const float* __restrict__ enc_b,
    const float* __restrict__ dec_b,
    const float* __restrict__ denseW,
    const float* __restrict__ denseb,
    float* __restrict__ out)
{
    __shared__ __align__(16) _Float16 hF[MB * KPAD];          // 9472 B
    __shared__ __align__(16) _Float16 Wlds[8][8][512];        // 65536 B
    __shared__ __align__(16) float    outS4[MB * COUT * 4];   // 2048 B

    const int tid  = threadIdx.x;
    const int w    = tid >> 6;       // 0..7 = ntile-pair id
    const int lane = tid & 63;
    const int quad = lane >> 4;
    const int l15  = lane & 15;
    const int n0   = blockIdx.x * MB;

    float bE[2][4], bD[2][4];
    #pragma unroll
    for (int p = 0; p < 2; ++p)
        #pragma unroll
        for (int g = 0; g < 4; ++g) {
            int col = (2 * w + p) * 16 + l15;
            bE[p][g] = enc_b[g * 256 + col];
            bD[p][g] = dec_b[g * 256 + col];
        }

    for (int i = tid; i < MB * KPAD; i += 512) hF[i] = (_Float16)0.0f;
    __syncthreads();
    if (tid < MB * CIN) {            // x for step 0 (256 threads)
        int m = tid >> 4, c = tid & 15;
        hF[m * KPAD + 256 + c] = (_Float16)x[(size_t)(n0 + m) * (CIN * TIN) + c * TIN];
    }
    __syncthreads();

    f32x4 acc[2][4];        // [pair][gate]
    float cst[2][4];        // [pair][row] c-state
    #pragma unroll
    for (int p = 0; p < 2; ++p)
        #pragma unroll
        for (int r = 0; r < 4; ++r) cst[p][r] = 0.0f;

    const f16x8* Ap0 = (const f16x8*)(hF + l15 * KPAD);   // single M-tile

    // frag f: kt = f>>3, g = (f>>1)&3, pair = f&1; slot = f&7 (static)
    auto stagef = [&](int f, const _Float16* __restrict__ Wbase) {
        int kt = f >> 3, g = (f >> 1) & 3, p = f & 1;
        const _Float16* gp =
            Wbase + (size_t)(kt * 64 + g * 16 + 2 * w + p) * 512 + lane * 8;
        gld_lds16(gp, &Wlds[w][f & 7][0]);
    };

    auto gemm = [&](auto kt_tag, const _Float16* __restrict__ Wbase,
                    const float (&bias)[2][4]) {
        constexpr int KT = decltype(kt_tag)::val;
        constexpr int NF = KT * 8;
        #pragma unroll
        for (int p = 0; p < 2; ++p)
            #pragma unroll
            for (int g = 0; g < 4; ++g) {
                float b = bias[p][g];
                f32x4 bv = {b, b, b, b};
                acc[p][g] = bv;
            }
        f16x8 a0;
        auto body = [&](int f) {       // f compile-time in all expansions
            int kt = f >> 3, g = (f >> 1) & 3, p = f & 1;
            if ((f & 7) == 0) a0 = Ap0[kt * 4 + quad];
            f16x8 bf = *(const f16x8*)&Wlds[w][f & 7][lane * 8];
            acc[p][g] = __builtin_amdgcn_mfma_f32_16x16x32_f16(a0, bf, acc[p][g], 0, 0, 0);
        };
        #pragma unroll
        for (int f = 0; f < 7; ++f) stagef(f, Wbase);   // fill ring
        #pragma unroll
        for (int f = 0; f < NF - 7; ++f) {
            // FENCE: body(f-1)'s ds_read of slot (f-1)&7 must not be passed
            // by stagef(f+7)'s DMA write to the same slot.
            __builtin_amdgcn_sched_barrier(0);
            stagef(f + 7, Wbase);
            asm volatile("s_waitcnt vmcnt(7)" ::: "memory");
            __builtin_amdgcn_sched_barrier(0);
            body(f);
        }
        asm volatile("s_waitcnt vmcnt(6)" ::: "memory"); __builtin_amdgcn_sched_barrier(0); body(NF - 7);
        asm volatile("s_waitcnt vmcnt(5)" ::: "memory"); __builtin_amdgcn_sched_barrier(0); body(NF - 6);
        asm volatile("s_waitcnt vmcnt(4)" ::: "memory"); __builtin_amdgcn_sched_barrier(0); body(NF - 5);
        asm volatile("s_waitcnt vmcnt(3)" ::: "memory"); __builtin_amdgcn_sched_barrier(0); body(NF - 4);
        asm volatile("s_waitcnt vmcnt(2)" ::: "memory"); __builtin_amdgcn_sched_barrier(0); body(NF - 3);
        asm volatile("s_waitcnt vmcnt(1)" ::: "memory"); __builtin_amdgcn_sched_barrier(0); body(NF - 2);
        asm volatile("s_waitcnt vmcnt(0)" ::: "memory"); __builtin_amdgcn_sched_barrier(0); body(NF - 1);
    };

    auto pointwise = [&]() {
        #pragma unroll
        for (int p = 0; p < 2; ++p) {
            int col = (2 * w + p) * 16 + l15;
            #pragma unroll
            for (int r = 0; r < 4; ++r) {
                float iv = sigm(acc[p][0][r]);
                float fv = sigm(acc[p][1][r]);
                float gv = tanh_f(acc[p][2][r]);
                float ov = sigm(acc[p][3][r]);
                float cn = fmaf(fv, cst[p][r], iv * gv);
                cst[p][r] = cn;
                float hv = ov * tanh_f(cn);
                hF[(quad * 4 + r) * KPAD + col] = (_Float16)hv;
            }
        }
    };

    // ================= encoder (r12 two-barrier scheme) =================
    for (int t = 0; t < TIN; ++t) {
        float xv = 0.0f;
        const bool xl = (tid < MB * CIN) && (t + 1 < TIN);
        if (xl)          // issued BEFORE the pipeline loads -> always older
            xv = x[(size_t)(n0 + (tid >> 4)) * (CIN * TIN) + (tid & 15) * TIN + (t + 1)];
        gemm(KTag<KT_ENC>{}, wf, bE);
        __syncthreads();              // all A-frag reads done
        pointwise();                  // write h_t
        if (xl) hF[(tid >> 4) * KPAD + 256 + (tid & 15)] = (_Float16)xv;
        __syncthreads();
    }

    // ================= decoder (c resets to 0) =================
    #pragma unroll
    for (int p = 0; p < 2; ++p)
        #pragma unroll
        for (int r = 0; r < 4; ++r) cst[p][r] = 0.0f;

    for (int t = 0; t < TOUT; ++t) {
        gemm(KTag<KT_DEC>{}, wf + WE_HALVES, bD);
        __syncthreads();
        pointwise();
        __syncthreads();
        // dense epilogue (threads 0..127 of 512). Reads complete before any
        // pointwise(t+1) write (barrier #1 of t+1 waits for these threads).
        // Epilogue junk VMEM is older than all of gemm(t+1)'s stages ->
        // retired by its first counted wait.
        if (tid < MB * COUT) {
            int m = tid >> 3, o = tid & 7;
            const float* wr = denseW + (t * COUT + o) * HD;
            float s = denseb[t * COUT + o];
            const _Float16* hrow = hF + m * KPAD;
            #pragma unroll 4
            for (int j8 = 0; j8 < 32; ++j8) {
                f16x8 hv  = *(const f16x8*)(hrow + j8 * 8);
                float4 w0 = *(const float4*)(wr + j8 * 8);
                float4 w1 = *(const float4*)(wr + j8 * 8 + 4);
                s = fmaf((float)hv[0], w0.x, s);
                s = fmaf((float)hv[1], w0.y, s);
                s = fmaf((float)hv[2], w0.z, s);
                s = fmaf((float)hv[3], w0.w, s);
                s = fmaf((float)hv[4], w1.x, s);
                s = fmaf((float)hv[5], w1.y, s);
                s = fmaf((float)hv[6], w1.z, s);
                s = fmaf((float)hv[7], w1.w, s);
            }
            outS4[(tid << 2) | (t & 3)] = s;
            if ((t & 3) == 3) {       // flush 4 finished t-values, 16B-aligned
                float4 v = *(const float4*)&outS4[tid << 2];
                *(float4*)(out + (size_t)(n0 + m) * (COUT * TOUT) + o * TOUT + (t - 3)) = v;
            }
        }
    }
}

extern "C" void kernel_launch(void* const* d_in, const int* in_sizes, int n_in,
                              void* d_out, int out_size, void* d_ws, size_t ws_size,
                              hipStream_t stream) {
    const float* x       = (const float*)d_in[0];
    const float* enc_Wih = (const float*)d_in[1];
    const float* enc_Whh = (const float*)d_in[2];
    const float* enc_b   = (const float*)d_in[3];
    const float* dec_Whh = (const float*)d_in[4];
    const float* dec_b   = (const float*)d_in[5];
    const float* denseW  = (const float*)d_in[6];
    const float* denseb  = (const float*)d_in[7];
    float* out = (float*)d_out;
    _Float16* wf = (_Float16*)d_ws;   // 1.09 MB fragment-major fp16 weights

    prep_frags<<<(PREP_TOTAL + 255) / 256, 256, 0, stream>>>(enc_Wih, enc_Whh, dec_Whh, wf);
    seq2seq_mfma<<<8192 / MB, 512, 0, stream>>>(x, wf, enc_b, dec_b, denseW, denseb, out);
}

// Round 17
// 1123.680 us; speedup vs baseline: 1.8981x; 1.8981x over previous
//
#include <hip/hip_runtime.h>

typedef __attribute__((ext_vector_type(8))) _Float16 f16x8;
typedef __attribute__((ext_vector_type(4))) float    f32x4;

#define HD    256
#define CIN   16
#define TIN   48
#define TOUT  24
#define COUT  8
#define MB    32            // batch rows per block
#define KPAD  296           // padded row stride (halves) for hF
#define KT_ENC 9            // K = 288 (h 256 | x 16 | pad 16)
#define KT_DEC 8            // K = 256
#define WE_HALVES (KT_ENC*4*16*512)   // 294912
#define WD_HALVES (KT_DEC*4*16*512)   // 262144
#define PREP_TOTAL (WE_HALVES + WD_HALVES)

template <int N> struct KTag { static constexpr int val = N; };

// Fragment-major fp16 weights: frag id = kt*64 + g*16 + ntile, each frag is
// 64 lanes x 8 halves with b_frag[lane][s] = W[k = kt*32 + (lane>>4)*8 + s]
//                                             [col = g*256 + ntile*16 + (lane&15)]
__global__ void prep_frags(const float* __restrict__ enc_Wih,
                           const float* __restrict__ enc_Whh,
                           const float* __restrict__ dec_Whh,
                           _Float16* __restrict__ wf)
{
    int p = blockIdx.x * blockDim.x + threadIdx.x;
    if (p >= PREP_TOTAL) return;
    int lane = (p >> 3) & 63;
    int s    = p & 7;
    int kq   = ((lane >> 4) << 3) + s;
    int l15  = lane & 15;
    float v;
    if (p < WE_HALVES) {
        int frag = p >> 9;
        int kt = frag >> 6, g = (frag >> 4) & 3, ntile = frag & 15;
        int k   = kt * 32 + kq;
        int row = g * 256 + ntile * 16 + l15;
        v = 0.0f;
        if (k < 256)      v = enc_Whh[row * 256 + k];
        else if (k < 272) v = enc_Wih[row * 16 + (k - 256)];
    } else {
        int q = p - WE_HALVES;
        int frag = q >> 9;
        int kt = frag >> 6, g = (frag >> 4) & 3, ntile = frag & 15;
        int k   = kt * 32 + kq;
        int row = g * 256 + ntile * 16 + l15;
        v = dec_Whh[row * 256 + k];
    }
    wf[p] = (_Float16)v;
}

__device__ __forceinline__ float sigm(float v) {
    return __builtin_amdgcn_rcpf(1.0f + __expf(-v));
}
__device__ __forceinline__ float tanh_f(float v) {
    return 1.0f - 2.0f * __builtin_amdgcn_rcpf(1.0f + __expf(2.0f * v));
}

// Async global->LDS stage of one 1KB weight fragment: 64 lanes x 16B.
__device__ __forceinline__ void gld_lds16(const _Float16* g, _Float16* l) {
    __builtin_amdgcn_global_load_lds(
        (const __attribute__((address_space(1))) void*)g,
        (__attribute__((address_space(3))) void*)l, 16, 0, 0);
}

// grid = 256 blocks (1/CU), 1024 threads = 16 waves. Wave w owns ntile w.
// Session-best structure (r12, 1125us): weights stream global->LDS via an
// 8-slot x 1KB per-frag ring per wave: stage frag f+7, wait vmcnt(7),
// consume frag f; tail waits 6..0. Counted waits never drain mid-loop. Junk
// VMEM (x preload / epilogue) is strictly older than pipeline loads ->
// conservative. Two __syncthreads() per step (proven barrier construct).
// Measured wall: per-CU weight-byte service ~15 B/cy (576KB/step -> 15.6us);
// co-residency (r6/r16) doubles demand at a fixed rate; per-CU bytes are
// structurally fixed by N/CU = 32 rows. LDS 154112 B.
__global__ __launch_bounds__(1024, 1) void seq2seq_mfma(
    const float* __restrict__ x,
    const _Float16* __restrict__ wf,
    const float* __restrict__ enc_b,
    const float* __restrict__ dec_b,
    const float* __restrict__ denseW,
    const float* __restrict__ denseb,
    float* __restrict__ out)
{
    __shared__ __align__(16) _Float16 hF[MB * KPAD];          // 18944 B
    __shared__ __align__(16) _Float16 Wlds[16][8][512];       // 131072 B
    __shared__ __align__(16) float    outS4[MB * COUT * 4];   // 4096 B

    const int tid  = threadIdx.x;
    const int w    = tid >> 6;       // 0..15 = ntile
    const int lane = tid & 63;
    const int quad = lane >> 4;
    const int l15  = lane & 15;
    const int n0   = blockIdx.x * MB;

    float bE[4], bD[4];
    #pragma unroll
    for (int g = 0; g < 4; ++g) {
        int col = w * 16 + l15;
        bE[g] = enc_b[g * 256 + col];
        bD[g] = dec_b[g * 256 + col];
    }

    for (int i = tid; i < MB * KPAD; i += 1024) hF[i] = (_Float16)0.0f;
    __syncthreads();
    if (tid < 512) {                 // x for step 0
        int m = tid >> 4, c = tid & 15;
        hF[m * KPAD + 256 + c] = (_Float16)x[(size_t)(n0 + m) * (CIN * TIN) + c * TIN];
    }
    __syncthreads();

    f32x4 acc[2][4];        // [Mtile][gate]
    float cst[2][4];        // c-state, C-frag layout rows
    #pragma unroll
    for (int mt = 0; mt < 2; ++mt)
        #pragma unroll
        for (int r = 0; r < 4; ++r) cst[mt][r] = 0.0f;

    const f16x8* Ap0 = (const f16x8*)(hF + l15 * KPAD);          // Mtile 0
    const f16x8* Ap1 = (const f16x8*)(hF + (16 + l15) * KPAD);   // Mtile 1

    // stage frag f (kt = f>>2, gate = f&3) into ring slot f&7
    auto stagef = [&](int f, const _Float16* __restrict__ Wbase) {
        int kt = f >> 2, g = f & 3;
        const _Float16* gp = Wbase + (size_t)(kt * 64 + g * 16 + w) * 512 + lane * 8;
        gld_lds16(gp, &Wlds[w][f & 7][0]);
    };

    auto gemm = [&](auto kt_tag, const _Float16* __restrict__ Wbase, const float (&bias)[4]) {
        constexpr int KT = decltype(kt_tag)::val;
        constexpr int NF = KT * 4;
        #pragma unroll
        for (int mt = 0; mt < 2; ++mt)
            #pragma unroll
            for (int g = 0; g < 4; ++g) {
                float b = bias[g];
                f32x4 bv = {b, b, b, b};
                acc[mt][g] = bv;
            }
        f16x8 a0, a1;
        auto body = [&](int f) {
            int kt = f >> 2, g = f & 3;
            if ((f & 3) == 0) {           // folds: f is compile-time constant
                a0 = Ap0[kt * 4 + quad];
                a1 = Ap1[kt * 4 + quad];
            }
            f16x8 bf = *(const f16x8*)&Wlds[w][f & 7][lane * 8];
            acc[0][g] = __builtin_amdgcn_mfma_f32_16x16x32_f16(a0, bf, acc[0][g], 0, 0, 0);
            acc[1][g] = __builtin_amdgcn_mfma_f32_16x16x32_f16(a1, bf, acc[1][g], 0, 0, 0);
        };
        #pragma unroll
        for (int f = 0; f < 7; ++f) stagef(f, Wbase);   // fill ring
        #pragma unroll
        for (int f = 0; f < NF - 7; ++f) {
            stagef(f + 7, Wbase);
            asm volatile("s_waitcnt vmcnt(7)" ::: "memory");
            __builtin_amdgcn_sched_barrier(0);
            body(f);
        }
        // tail: frags NF-7 .. NF-1, waits 6..0 (full drain at the end)
        asm volatile("s_waitcnt vmcnt(6)" ::: "memory"); __builtin_amdgcn_sched_barrier(0); body(NF - 7);
        asm volatile("s_waitcnt vmcnt(5)" ::: "memory"); __builtin_amdgcn_sched_barrier(0); body(NF - 6);
        asm volatile("s_waitcnt vmcnt(4)" ::: "memory"); __builtin_amdgcn_sched_barrier(0); body(NF - 5);
        asm volatile("s_waitcnt vmcnt(3)" ::: "memory"); __builtin_amdgcn_sched_barrier(0); body(NF - 4);
        asm volatile("s_waitcnt vmcnt(2)" ::: "memory"); __builtin_amdgcn_sched_barrier(0); body(NF - 3);
        asm volatile("s_waitcnt vmcnt(1)" ::: "memory"); __builtin_amdgcn_sched_barrier(0); body(NF - 2);
        asm volatile("s_waitcnt vmcnt(0)" ::: "memory"); __builtin_amdgcn_sched_barrier(0); body(NF - 1);
    };

    auto pointwise = [&]() {
        int col = w * 16 + l15;
        #pragma unroll
        for (int mt = 0; mt < 2; ++mt)
            #pragma unroll
            for (int r = 0; r < 4; ++r) {
                float iv = sigm(acc[mt][0][r]);
                float fv = sigm(acc[mt][1][r]);
                float gv = tanh_f(acc[mt][2][r]);
                float ov = sigm(acc[mt][3][r]);
                float cn = fmaf(fv, cst[mt][r], iv * gv);
                cst[mt][r] = cn;
                float hv = ov * tanh_f(cn);
                hF[(mt * 16 + quad * 4 + r) * KPAD + col] = (_Float16)hv;
            }
    };

    // ================= encoder =================
    for (int t = 0; t < TIN; ++t) {
        float xv = 0.0f;
        const bool xl = (tid < 512) && (t + 1 < TIN);
        if (xl)          // issued BEFORE the pipeline loads -> always older
            xv = x[(size_t)(n0 + (tid >> 4)) * (CIN * TIN) + (tid & 15) * TIN + (t + 1)];
        gemm(KTag<KT_ENC>{}, wf, bE);
        __syncthreads();              // all A-frag reads done
        pointwise();                  // write h_t
        if (xl) hF[(tid >> 4) * KPAD + 256 + (tid & 15)] = (_Float16)xv;
        __syncthreads();
    }

    // ================= decoder (c resets to 0) =================
    #pragma unroll
    for (int mt = 0; mt < 2; ++mt)
        #pragma unroll
        for (int r = 0; r < 4; ++r) cst[mt][r] = 0.0f;

    for (int t = 0; t < TOUT; ++t) {
        gemm(KTag<KT_DEC>{}, wf + WE_HALVES, bD);
        __syncthreads();
        pointwise();
        __syncthreads();
        // dense epilogue (threads 0..255). hF is read-only until the next
        // step's post-gemm barrier -> race-free. outS4 slots thread-private.
        if (tid < MB * COUT) {
            int m = tid >> 3, o = tid & 7;
            const float* wr = denseW + (t * COUT + o) * HD;
            float s = denseb[t * COUT + o];
            #pragma unroll 4
            for (int j8 = 0; j8 < 32; ++j8) {
                f16x8 hv  = *(const f16x8*)(hF + m * KPAD + j8 * 8);
                float4 w0 = *(const float4*)(wr + j8 * 8);
                float4 w1 = *(const float4*)(wr + j8 * 8 + 4);
                s = fmaf((float)hv[0], w0.x, s);
                s = fmaf((float)hv[1], w0.y, s);
                s = fmaf((float)hv[2], w0.z, s);
                s = fmaf((float)hv[3], w0.w, s);
                s = fmaf((float)hv[4], w1.x, s);
                s = fmaf((float)hv[5], w1.y, s);
                s = fmaf((float)hv[6], w1.z, s);
                s = fmaf((float)hv[7], w1.w, s);
            }
            outS4[(tid << 2) | (t & 3)] = s;
            if ((t & 3) == 3) {       // flush 4 finished t-values, 16B-aligned
                float4 v = *(const float4*)&outS4[tid << 2];
                *(float4*)(out + (size_t)(n0 + m) * (COUT * TOUT) + o * TOUT + (t - 3)) = v;
            }
        }
    }
}

extern "C" void kernel_launch(void* const* d_in, const int* in_sizes, int n_in,
                              void* d_out, int out_size, void* d_ws, size_t ws_size,
                              hipStream_t stream) {
    const float* x       = (const float*)d_in[0];
    const float* enc_Wih = (const float*)d_in[1];
    const float* enc_Whh = (const float*)d_in[2];
    const float* enc_b   = (const float*)d_in[3];
    const float* dec_Whh = (const float*)d_in[4];
    const float* dec_b   = (const float*)d_in[5];
    const float* denseW  = (const float*)d_in[6];
    const float* denseb  = (const float*)d_in[7];
    float* out = (float*)d_out;
    _Float16* wf = (_Float16*)d_ws;   // 1.09 MB fragment-major fp16 weights

    prep_frags<<<(PREP_TOTAL + 255) / 256, 256, 0, stream>>>(enc_Wih, enc_Whh, dec_Whh, wf);
    seq2seq_mfma<<<8192 / MB, 1024, 0, stream>>>(x, wf, enc_b, dec_b, denseW, denseb, out);
}